// Round 8
// baseline (1183.416 us; speedup 1.0000x reference)
//
#include <hip/hip_runtime.h>
#include <hip/hip_cooperative_groups.h>
#include <hip/hip_bf16.h>

namespace cg = cooperative_groups;

#define N_NODES 5000
#define N_EDGES 80000
#define BATCH   32
#define FDIM    64
#define BF      (BATCH * FDIM)   // 2048
#define GRID_BLKS 1024           // 4 blocks/CU co-resident (launch_bounds 256,4)
#define NSPREAD 16               // pooled contention spread

// ---- workspace layout (bytes) ----
#define OFF_DEG      0           // int[5000]
#define OFF_FILL     20480       // int[5000]
#define OFF_POOLEDP  40960       // float[NSPREAD*2048] = 131072
#define ZERO_BYTES   172032
#define OFF_DINV     172032      // float[5000]
#define OFF_ROWPTR   192512      // int[5001]
#define OFF_EDGES    212992      // int[160000]
#define OFF_COL      852992      // int[80000]
#define OFF_VAL      1172992     // float[80000]
#define OFF_XT       1492992     // float[5000*32]
#define OFF_S        2132992     // float[5000*32]
#define OFF_W2H      2772992     // short[4096]  W2 hi, transposed [f][k]
#define OFF_W2L      2781184     // short[4096]  W2 lo, transposed [f][k]

typedef __attribute__((ext_vector_type(8))) short short8;
typedef __attribute__((ext_vector_type(4))) float f32x4;

__device__ inline short f2bf(float f) {           // RTNE f32 -> bf16 bits
    unsigned u = __builtin_bit_cast(unsigned, f);
    unsigned r = (u + 0x7fffu + ((u >> 16) & 1u)) >> 16;
    return (short)r;
}
__device__ inline float bf2f(short h) {
    unsigned u = ((unsigned)(unsigned short)h) << 16;
    return __builtin_bit_cast(float, u);
}

// phase==0: full pipeline with grid.sync (cooperative). phase==1..6: that phase only
// (fallback path when cooperative launch is unavailable).
__global__ __launch_bounds__(256, 4) void mega(
        const unsigned int* __restrict__ raw, const float* __restrict__ x,
        const float* __restrict__ W1, const float* __restrict__ b1,
        const float* __restrict__ W2, const float* __restrict__ b2,
        const float* __restrict__ Wmu, const float* __restrict__ bmu,
        const float* __restrict__ Wlv, const float* __restrict__ blv,
        float* __restrict__ out, char* __restrict__ ws, int phase) {
    int*   deg     = (int*)(ws + OFF_DEG);
    int*   fill    = (int*)(ws + OFF_FILL);
    float* pooledP = (float*)(ws + OFF_POOLEDP);
    float* dinv    = (float*)(ws + OFF_DINV);
    int*   rowp    = (int*)(ws + OFF_ROWPTR);
    int*   edges   = (int*)(ws + OFF_EDGES);
    int*   col     = (int*)(ws + OFF_COL);
    float* val     = (float*)(ws + OFF_VAL);
    float* xT      = (float*)(ws + OFF_XT);
    float* s       = (float*)(ws + OFF_S);
    short* w2hT    = (short*)(ws + OFF_W2H);
    short* w2lT    = (short*)(ws + OFF_W2L);

    __shared__ float shmem[64 * 33];   // 8448B: scan part / aggs[64][33] / pb[2048]
    const bool all = (phase == 0);
    int tid = threadIdx.x;

    // ---- P1: edge convert+degree, x transpose, W2 bf16 hi/lo split ----
    if (all || phase == 1) {
        unsigned int hi = raw[2 * (tid & 63) + 1];
        bool is64 = (__ballot(hi == 0u) == ~0ull);
        int i = blockIdx.x * 256 + tid;
        if (i < 2 * N_EDGES) {
            int v = is64 ? (int)raw[2 * i] : (int)raw[i];
            edges[i] = v;
            if (i >= N_EDGES) atomicAdd(&deg[v], 1);
        }
        if (i < BATCH * N_NODES) {
            int b = i / N_NODES, n = i - b * N_NODES;
            xT[n * BATCH + b] = x[i];
        }
        if (i < FDIM * FDIM) {
            float w = W2[i];
            int k = i >> 6, f = i & 63;
            short h = f2bf(w);
            w2hT[f * 64 + k] = h;
            w2lT[f * 64 + k] = f2bf(w - bf2f(h));
        }
    }
    if (all) { __threadfence(); cg::this_grid().sync(); }

    // ---- P2: block 0 scans deg -> rowp, computes dinv ----
    if (all || phase == 2) {
        if (blockIdx.x == 0) {
            int* part = (int*)shmem;
            int lv[20];
            int base = tid * 20;
            int sum = 0;
#pragma unroll
            for (int u = 0; u < 20; u++) {
                int idx = base + u;
                int v = 0;
                if (idx < N_NODES) {
                    v = deg[idx];
                    dinv[idx] = 1.0f / sqrtf((float)v + 1.0f);  // +1 self-loop
                }
                lv[u] = sum;
                sum += v;
            }
            part[tid] = sum;
            __syncthreads();
            for (int off = 1; off < 256; off <<= 1) {
                int v = (tid >= off) ? part[tid - off] : 0;
                __syncthreads();
                part[tid] += v;
                __syncthreads();
            }
            int prefix = (tid > 0) ? part[tid - 1] : 0;
#pragma unroll
            for (int u = 0; u < 20; u++) {
                int idx = base + u;
                if (idx < N_NODES) rowp[idx] = prefix + lv[u];
            }
            if (tid == 255) rowp[N_NODES] = part[255];
        }
    }
    if (all) { __threadfence(); cg::this_grid().sync(); }

    // ---- P3: fill CSR ----
    if (all || phase == 3) {
        int e = blockIdx.x * 256 + tid;
        if (e < N_EDGES) {
            int sc = edges[e];
            int d = edges[N_EDGES + e];
            int pos = atomicAdd(&fill[d], 1);
            int idx = rowp[d] + pos;
            col[idx] = sc;
            val[idx] = dinv[sc] * dinv[d];
        }
    }
    if (all) { __threadfence(); cg::this_grid().sync(); }

    // ---- P4: s = Â x (width-32 SpMM, 8-deep prefetch) ----
    if (all || phase == 4) {
        int g32 = tid >> 5, lane = tid & 31;
        int n = blockIdx.x * 8 + g32;
        if (n < N_NODES) {
            float dv = dinv[n];
            float acc = dv * dv * xT[n * BATCH + lane];
            int beg = rowp[n], end = rowp[n + 1];
            for (int i = beg; i < end; i += 8) {
                float pv[8], wv[8];
#pragma unroll
                for (int u = 0; u < 8; u++) {
                    int e = i + u;
                    int c = (e < end) ? col[e] : n;
                    wv[u] = (e < end) ? val[e] : 0.0f;
                    pv[u] = xT[c * BATCH + lane];
                }
#pragma unroll
                for (int u = 0; u < 8; u++) acc = fmaf(wv[u], pv[u], acc);
            }
            s[n * BATCH + lane] = acc;
        }
    }
    if (all) { __threadfence(); cg::this_grid().sync(); }

    // ---- P5: fused layer-1 recompute + layer-2 agg + MFMA GEMM + out write ----
    if (all || phase == 5) {
        int g = tid >> 5, b = tid & 31;
        int lane = tid & 63, wave = tid >> 6;
        int c = lane & 15, q = lane >> 4;
        int mt = wave >> 1;
        int nt0 = (wave & 1) * 2;
        float (*aggs)[33] = (float(*)[33])shmem;

        float w1r[8], b1r[8];
#pragma unroll
        for (int j = 0; j < 8; j++) { w1r[j] = W1[g * 8 + j]; b1r[j] = b1[g * 8 + j]; }
        short8 bhf[2][2], blf[2][2];   // [nti][kt] — hoisted, once per block
#pragma unroll
        for (int nti = 0; nti < 2; nti++)
#pragma unroll
            for (int kt = 0; kt < 2; kt++) {
                int f = (nt0 + nti) * 16 + c;
                bhf[nti][kt] = *(const short8*)&w2hT[f * 64 + kt * 32 + q * 8];
                blf[nti][kt] = *(const short8*)&w2lT[f * 64 + kt * 32 + q * 8];
            }
        float p8[8];
#pragma unroll
        for (int u = 0; u < 8; u++) p8[u] = 0.0f;

        for (int n = blockIdx.x; n < N_NODES; n += GRID_BLKS) {
            float dv = dinv[n];
            float dv2 = dv * dv;
            float sv0 = s[n * BATCH + b];
            float acc[8];
#pragma unroll
            for (int j = 0; j < 8; j++)
                acc[j] = dv2 * fmaxf(fmaf(sv0, w1r[j], b1r[j]), 0.0f);
            int beg = rowp[n], end = rowp[n + 1];
            for (int i = beg; i < end; i += 8) {
                float sv[8], wv[8];
#pragma unroll
                for (int u = 0; u < 8; u++) {
                    int e = i + u;
                    int c2 = (e < end) ? col[e] : n;
                    wv[u] = (e < end) ? val[e] : 0.0f;
                    sv[u] = s[c2 * BATCH + b];
                }
#pragma unroll
                for (int u = 0; u < 8; u++)
#pragma unroll
                    for (int j = 0; j < 8; j++)
                        acc[j] = fmaf(wv[u], fmaxf(fmaf(sv[u], w1r[j], b1r[j]), 0.0f), acc[j]);
            }
            __syncthreads();   // previous iteration's aggs reads complete
#pragma unroll
            for (int j = 0; j < 8; j++) aggs[g * 8 + j][b] = acc[j];
            __syncthreads();

            short8 ah[2], al[2];
            int brow = mt * 16 + c;
#pragma unroll
            for (int kt = 0; kt < 2; kt++)
#pragma unroll
                for (int j = 0; j < 8; j++) {
                    float a = aggs[kt * 32 + q * 8 + j][brow];
                    short h = f2bf(a);
                    ah[kt][j] = h;
                    al[kt][j] = f2bf(a - bf2f(h));
                }
            f32x4 dacc[2];
#pragma unroll
            for (int nti = 0; nti < 2; nti++) dacc[nti] = (f32x4){0.f, 0.f, 0.f, 0.f};
#pragma unroll
            for (int nti = 0; nti < 2; nti++)
#pragma unroll
                for (int kt = 0; kt < 2; kt++) {
                    dacc[nti] = __builtin_amdgcn_mfma_f32_16x16x32_bf16(al[kt], bhf[nti][kt], dacc[nti], 0, 0, 0);
                    dacc[nti] = __builtin_amdgcn_mfma_f32_16x16x32_bf16(ah[kt], blf[nti][kt], dacc[nti], 0, 0, 0);
                    dacc[nti] = __builtin_amdgcn_mfma_f32_16x16x32_bf16(ah[kt], bhf[nti][kt], dacc[nti], 0, 0, 0);
                }
#pragma unroll
            for (int nti = 0; nti < 2; nti++) {
                int f = (nt0 + nti) * 16 + c;
                float bias = b2[f];
#pragma unroll
                for (int r = 0; r < 4; r++) {
                    int bb = mt * 16 + q * 4 + r;
                    float v = fmaxf(dacc[nti][r] + bias, 0.0f);
                    out[2 * BF + (size_t)bb * (N_NODES * FDIM) + n * FDIM + f] = v;
                    p8[nti * 4 + r] += v;
                }
            }
        }
        // one pooled atomic sweep per thread (8 values), spread over NSPREAD copies
#pragma unroll
        for (int nti = 0; nti < 2; nti++)
#pragma unroll
            for (int r = 0; r < 4; r++) {
                int f = (nt0 + nti) * 16 + c;
                int bb = mt * 16 + q * 4 + r;
                atomicAdd(&pooledP[(blockIdx.x & (NSPREAD - 1)) * BF + bb * 64 + f],
                          p8[nti * 4 + r]);
            }
    }
    if (all) { __threadfence(); cg::this_grid().sync(); }

    // ---- P6: block 0 reduces pooled copies + both heads ----
    if (all || phase == 6) {
        if (blockIdx.x == 0) {
            float* pb = shmem;
#pragma unroll
            for (int sg = 0; sg < 8; sg++) {
                int id = tid + sg * 256;
                float a = 0.f;
#pragma unroll
                for (int cc = 0; cc < NSPREAD; cc++) a += pooledP[cc * BF + id];
                pb[id] = a * (1.0f / 5000.0f);
            }
            __syncthreads();
#pragma unroll
            for (int sg = 0; sg < 8; sg++) {
                int id = tid + sg * 256;
                int b = id >> 6, f = id & 63;
                float mu = bmu[f], lv = blv[f];
#pragma unroll 8
                for (int k = 0; k < 64; k++) {
                    float p = pb[b * 64 + k];
                    mu = fmaf(p, Wmu[k * 64 + f], mu);
                    lv = fmaf(p, Wlv[k * 64 + f], lv);
                }
                out[id] = mu;
                out[BF + id] = lv;
            }
        }
    }
}

extern "C" void kernel_launch(void* const* d_in, const int* in_sizes, int n_in,
                              void* d_out, int out_size, void* d_ws, size_t ws_size,
                              hipStream_t stream) {
    const float* x   = (const float*)d_in[0];
    const unsigned int* era = (const unsigned int*)d_in[1];
    const float* W1  = (const float*)d_in[2];
    const float* b1  = (const float*)d_in[3];
    const float* W2  = (const float*)d_in[4];
    const float* b2  = (const float*)d_in[5];
    const float* Wmu = (const float*)d_in[6];
    const float* bmu = (const float*)d_in[7];
    const float* Wlv = (const float*)d_in[8];
    const float* blv = (const float*)d_in[9];
    float* out = (float*)d_out;
    char*  ws  = (char*)d_ws;

    hipMemsetAsync(ws, 0, ZERO_BYTES, stream);

    int phase0 = 0;
    void* args[] = { (void*)&era, (void*)&x, (void*)&W1, (void*)&b1, (void*)&W2,
                     (void*)&b2, (void*)&Wmu, (void*)&bmu, (void*)&Wlv, (void*)&blv,
                     (void*)&out, (void*)&ws, (void*)&phase0 };
    hipError_t err = hipLaunchCooperativeKernel((const void*)mega, dim3(GRID_BLKS),
                                                dim3(256), args, 0, stream);
    if (err != hipSuccess) {
        // fallback: same phases as sequential launches (implicit inter-kernel sync)
        for (int p = 1; p <= 6; p++)
            mega<<<GRID_BLKS, 256, 0, stream>>>(era, x, W1, b1, W2, b2,
                                                Wmu, bmu, Wlv, blv, out, ws, p);
    }
}